// Round 7
// baseline (439.225 us; speedup 1.0000x reference)
//
#include <hip/hip_runtime.h>
#include <hip/hip_bf16.h>

#define TSEQ 2048
#define HID 384
#define NHEAD 4
#define HD 96
#define NBATCH 8

using bf16 = __bf16;
typedef bf16 bf16x8 __attribute__((ext_vector_type(8)));
typedef bf16 bf16x4 __attribute__((ext_vector_type(4)));
typedef float f32x4 __attribute__((ext_vector_type(4)));

static __device__ __forceinline__ f32x4 mfma16(bf16x8 a, bf16x8 b, f32x4 c) {
    return __builtin_amdgcn_mfma_f32_16x16x32_bf16(a, b, c, 0, 0, 0);
}

// same-wave LDS handoff: wait ds_writes without draining vmcnt; DS ops pinned
// on both sides, VMEM/VALU/MFMA may cross (mask 0x7F = all but DS*).
#define LDS_HANDOFF()                                   \
    __builtin_amdgcn_sched_barrier(0x7F);               \
    asm volatile("s_waitcnt lgkmcnt(0)");               \
    __builtin_amdgcn_sched_barrier(0x7F)

// ---------------- conversion kernels ----------------
__global__ void k_conv8(const float* __restrict__ src, bf16* __restrict__ dst, int n8) {
    int t = blockIdx.x * 256 + threadIdx.x;
    if (t >= n8) return;
    const float4* s4 = reinterpret_cast<const float4*>(src);
    float4 a = s4[2 * t], b = s4[2 * t + 1];
    bf16x8 o;
    o[0] = (bf16)a.x; o[1] = (bf16)a.y; o[2] = (bf16)a.z; o[3] = (bf16)a.w;
    o[4] = (bf16)b.x; o[5] = (bf16)b.y; o[6] = (bf16)b.z; o[7] = (bf16)b.w;
    *reinterpret_cast<bf16x8*>(dst + 8 * t) = o;
}

__global__ void k_convT(const float* __restrict__ W, bf16* __restrict__ WT) {
    int t = blockIdx.x * 256 + threadIdx.x;  // WT[n][k] = W[k][n]
    int n = t / HID, k = t % HID;
    WT[t] = (bf16)W[(size_t)k * HID + n];
}

// ---------------- projection GEMM (Q,K,V,pos) ----------------
__launch_bounds__(256, 2)
__global__ void k_proj(const bf16* __restrict__ X, const bf16* __restrict__ P,
                       const bf16* __restrict__ wqT, const bf16* __restrict__ wkT,
                       const bf16* __restrict__ wvT, const bf16* __restrict__ wpT,
                       const float* __restrict__ bq, const float* __restrict__ bk,
                       const float* __restrict__ bv,
                       const float* __restrict__ pbu, const float* __restrict__ pbv,
                       bf16* __restrict__ qu, bf16* __restrict__ qv,
                       bf16* __restrict__ kws, bf16* __restrict__ vt,
                       bf16* __restrict__ pp) {
    __shared__ bf16 wt_lds[96][392];
    const float SC = 0.10206207262f;  // 1/sqrt(96) folded into q
    int mat = blockIdx.z;             // 0=Q 1=K 2=V 3=POS
    int m0 = blockIdx.x * 64;
    if (mat == 3 && m0 >= 4095) return;
    int n0 = blockIdx.y * 96;
    const bf16* A  = (mat == 3) ? P : X;
    const bf16* WT = (mat == 0) ? wqT : (mat == 1) ? wkT : (mat == 2) ? wvT : wpT;
    int tid = threadIdx.x;
    #pragma unroll
    for (int s = 0; s < 18; ++s) {
        int cc = tid + 256 * s;
        int r = cc / 48, ch = cc % 48;
        *reinterpret_cast<int4*>(&wt_lds[r][ch * 8]) =
            *reinterpret_cast<const int4*>(WT + (size_t)(n0 + r) * HID + ch * 8);
    }
    __syncthreads();
    int lane = tid & 63, w = tid >> 6;
    int c = lane & 15, g = lane >> 4;
    int arow = m0 + 16 * w + c;
    if (mat == 3 && arow > 4095) arow = 4095;
    const bf16* Abase = A + (size_t)arow * HID + 8 * g;
    f32x4 acc[6] = {};
    for (int ks = 0; ks < 12; ++ks) {
        bf16x8 a = *reinterpret_cast<const bf16x8*>(Abase + 32 * ks);
        #pragma unroll
        for (int jt = 0; jt < 6; ++jt) {
            bf16x8 b = *reinterpret_cast<const bf16x8*>(&wt_lds[16 * jt + c][32 * ks + 8 * g]);
            acc[jt] = mfma16(a, b, acc[jt]);
        }
    }
    int h = blockIdx.y;
    int rbase = m0 + 16 * w + 4 * g;
    if (mat == 0) {
        #pragma unroll
        for (int jt = 0; jt < 6; ++jt) {
            int n = n0 + 16 * jt + c;
            int d = 16 * jt + c;
            float bb = bq[n], bu = pbu[n], bvv = pbv[n];
            #pragma unroll
            for (int j = 0; j < 4; ++j) {
                int m = rbase + j;
                int b_ = m >> 11, t = m & 2047;
                size_t o = (((size_t)(b_ * NHEAD + h)) * TSEQ + t) * HD + d;
                float q = acc[jt][j] + bb;
                qu[o] = (bf16)((q + bu) * SC);
                qv[o] = (bf16)((q + bvv) * SC);
            }
        }
    } else if (mat == 1) {
        #pragma unroll
        for (int jt = 0; jt < 6; ++jt) {
            int n = n0 + 16 * jt + c;
            int d = 16 * jt + c;
            float bb = bk[n];
            #pragma unroll
            for (int j = 0; j < 4; ++j) {
                int m = rbase + j;
                int b_ = m >> 11, t = m & 2047;
                size_t o = (((size_t)(b_ * NHEAD + h)) * TSEQ + t) * HD + d;
                kws[o] = (bf16)(acc[jt][j] + bb);
            }
        }
    } else if (mat == 2) {
        #pragma unroll
        for (int jt = 0; jt < 6; ++jt) {
            int d = 16 * jt + c;
            float bb = bv[n0 + 16 * jt + c];
            int m = rbase;
            int b_ = m >> 11, t0 = m & 2047;
            size_t o = (((size_t)(b_ * NHEAD + h)) * HD + d) * TSEQ + t0;
            bf16x4 pk;
            #pragma unroll
            for (int j = 0; j < 4; ++j) pk[j] = (bf16)(acc[jt][j] + bb);
            *reinterpret_cast<bf16x4*>(vt + o) = pk;
        }
    } else {
        #pragma unroll
        for (int jt = 0; jt < 6; ++jt) {
            int d = 16 * jt + c;
            #pragma unroll
            for (int j = 0; j < 4; ++j) {
                int m = rbase + j;
                if (m < 4095) {
                    size_t o = ((size_t)h * 4096 + m) * HD + d;
                    pp[o] = (bf16)acc[jt][j];
                }
            }
        }
    }
}

// ---------------- fused rel-pos flash attention (transposed-S, all-global) ----
// grid 1024 = 8 XCD groups x 128; per-XCD working set (K/V 4 pairs + pos head)
// ~3.8MB -> L2-resident. K, V^T and pos MFMA A-frags gathered DIRECTLY from
// global (L2) — no K/V LDS staging, no msk_lds, NO __syncthreads in the loop:
// waves are fully independent. Only LDS use: per-wave win/P diagonal buffer.
// S^T = mfma(K,Qu): lane(c,g) reg(t,j) holds S^T[k=16t+4g+j][q=c].
// Win tile t=4 of iter kt == t=0 of kt+1 -> register carry (saves 3 MFMA+loads).
__launch_bounds__(256, 4)
__global__ void k_attn(const bf16* __restrict__ qu, const bf16* __restrict__ qv,
                       const bf16* __restrict__ kws, const bf16* __restrict__ vt,
                       const bf16* __restrict__ pp, const int* __restrict__ mask,
                       bf16* __restrict__ out) {
    __shared__ bf16 wp_lds[4][16][104];   // win (skew c+1) THEN P — time-disjoint alias

    int bid = blockIdx.x;
    // XCD-local decode: XCD x = bid&7 gets head h=x&3, batches (x>>2)*4 + (j5>>5)
    int x = bid & 7, j5 = bid >> 3;
    int h = x & 3;
    int b_ = (x >> 2) * 4 + (j5 >> 5);
    int qb = j5 & 31;
    int bh = b_ * NHEAD + h;
    int q0 = qb * 64;

    int tid = threadIdx.x, lane = tid & 63, w = tid >> 6;
    int c = lane & 15, g = lane >> 4;
    const int n_base0 = TSEQ - 1 - 63 - q0;  // lowest pos row for kt=0
    const float L2E = 1.44269504089f;
    int sw = 48 - 16 * w;                    // wave's window start offset

    const bf16* kbP = kws + (size_t)bh * TSEQ * HD;
    const bf16* vbP = vt + (size_t)bh * HD * TSEQ;
    const bf16* pbP = pp + (size_t)h * 4096 * HD;
    const int*  mbP = mask + b_ * TSEQ;

    bf16x8 qu_f[3], qv_f[3];
    {
        size_t rowbase = ((size_t)bh * TSEQ + q0 + 16 * w + c) * HD + 8 * g;
        #pragma unroll
        for (int ds = 0; ds < 3; ++ds) {
            qu_f[ds] = *reinterpret_cast<const bf16x8*>(qu + rowbase + 32 * ds);
            qv_f[ds] = *reinterpret_cast<const bf16x8*>(qv + rowbase + 32 * ds);
        }
    }

    f32x4 acc_o[6] = {};
    float mrow = -3.0e38f, lrow = 0.f;

    // ---- win carry: tile t=0 of kt=0 ----
    f32x4 wc = {};
    {
        const bf16* p0 = pbP + (size_t)(n_base0 + sw + c) * HD + 8 * g;
        #pragma unroll
        for (int ds = 0; ds < 3; ++ds)
            wc = mfma16(*reinterpret_cast<const bf16x8*>(p0 + 32 * ds), qv_f[ds], wc);
    }

    for (int kt = 0; kt < 32; ++kt) {
        int k0 = kt * 64;
        int wbase = n_base0 + 64 * kt + sw;
        unsigned long long bm = __ballot(mbP[k0 + lane] != 0);

        // ---- spill carry as tile 0; compute win tiles 1..4 (pairs); wc <- t4
        #pragma unroll
        for (int j = 0; j < 4; ++j)
            wp_lds[w][c][4 * g + j + c + 1] = (bf16)wc[j];
        {
            f32x4 w1 = {}, w2 = {};
            const bf16* p1 = pbP + (size_t)(wbase + 16 + c) * HD + 8 * g;
            const bf16* p2 = pbP + (size_t)(wbase + 32 + c) * HD + 8 * g;
            #pragma unroll
            for (int ds = 0; ds < 3; ++ds) {
                w1 = mfma16(*reinterpret_cast<const bf16x8*>(p1 + 32 * ds), qv_f[ds], w1);
                w2 = mfma16(*reinterpret_cast<const bf16x8*>(p2 + 32 * ds), qv_f[ds], w2);
            }
            #pragma unroll
            for (int j = 0; j < 4; ++j) {
                wp_lds[w][c][16 + 4 * g + j + c + 1] = (bf16)w1[j];
                wp_lds[w][c][32 + 4 * g + j + c + 1] = (bf16)w2[j];
            }
        }
        {
            f32x4 w3 = {}, w4 = {};
            const bf16* p3 = pbP + (size_t)(wbase + 48 + c) * HD + 8 * g;
            const bf16* p4 = pbP + (size_t)(wbase + 64 + c) * HD + 8 * g;
            #pragma unroll
            for (int ds = 0; ds < 3; ++ds) {
                w3 = mfma16(*reinterpret_cast<const bf16x8*>(p3 + 32 * ds), qv_f[ds], w3);
                w4 = mfma16(*reinterpret_cast<const bf16x8*>(p4 + 32 * ds), qv_f[ds], w4);
            }
            #pragma unroll
            for (int j = 0; j < 4; ++j) {
                wp_lds[w][c][48 + 4 * g + j + c + 1] = (bf16)w3[j];
                wp_lds[w][c][64 + 4 * g + j + c + 1] = (bf16)w4[j];
            }
            wc = w4;
        }

        // ---- content scores S^T: K A-frags direct from global (L2) ----
        __builtin_amdgcn_s_setprio(1);
        f32x4 acc_s[4] = {};
        #pragma unroll
        for (int ds = 0; ds < 3; ++ds) {
            #pragma unroll
            for (int t = 0; t < 4; ++t) {
                bf16x8 a = *reinterpret_cast<const bf16x8*>(
                    kbP + (size_t)(k0 + 16 * t + c) * HD + 32 * ds + 8 * g);
                acc_s[t] = mfma16(a, qu_f[ds], acc_s[t]);
            }
        }
        __builtin_amdgcn_s_setprio(0);

        LDS_HANDOFF();  // win spills -> diagonal gather (cross-lane, same wave)

        // ---- assemble in place + mask + online softmax (per-lane row q=c) ----
        #pragma unroll
        for (int t = 0; t < 4; ++t) {
            bf16x4 wv = *reinterpret_cast<const bf16x4*>(&wp_lds[w][c][16 * t + 4 * g + 16]);
            acc_s[t][0] += (float)wv[0];
            acc_s[t][1] += (float)wv[1];
            acc_s[t][2] += (float)wv[2];
            acc_s[t][3] += (float)wv[3];
        }
        if (bm != ~0ull) {  // wave-uniform skip: mask rarely sparse
            #pragma unroll
            for (int t = 0; t < 4; ++t)
                #pragma unroll
                for (int j = 0; j < 4; ++j)
                    if (!((bm >> (16 * t + 4 * g + j)) & 1)) acc_s[t][j] = -3.0e38f;
        }
        float pm = acc_s[0][0];
        #pragma unroll
        for (int t = 0; t < 4; ++t)
            #pragma unroll
            for (int j = 0; j < 4; ++j) pm = fmaxf(pm, acc_s[t][j]);
        pm = fmaxf(pm, __shfl_xor(pm, 16));
        pm = fmaxf(pm, __shfl_xor(pm, 32));
        if (!__all(pm <= mrow + 8.0f)) {   // defer-max (THR=8)
            float mnew = fmaxf(mrow, pm);
            float alpha = exp2f((mrow - mnew) * L2E);
            mrow = mnew; lrow *= alpha;
            #pragma unroll
            for (int ot = 0; ot < 6; ++ot) acc_o[ot] *= alpha;
        }
        float rs = 0.f;
        #pragma unroll
        for (int t = 0; t < 4; ++t)
            #pragma unroll
            for (int j = 0; j < 4; ++j) {
                float p = exp2f((acc_s[t][j] - mrow) * L2E);
                acc_s[t][j] = p; rs += p;
            }
        rs += __shfl_xor(rs, 16);
        rs += __shfl_xor(rs, 32);
        lrow += rs;

        // ---- P -> LDS (col-major [q][k], aligned b64), aliases win buffer ----
        // (win reads above precede these writes in program order; same wave)
        #pragma unroll
        for (int t = 0; t < 4; ++t) {
            bf16x4 pk;
            #pragma unroll
            for (int j = 0; j < 4; ++j) pk[j] = (bf16)acc_s[t][j];
            *reinterpret_cast<bf16x4*>(&wp_lds[w][c][16 * t + 4 * g]) = pk;
        }

        LDS_HANDOFF();  // P spills -> PV B-frags (cross-lane, same wave)

        // ---- PV: O^T += V^T . P ; V^T A-frags direct from global (L2) ----
        __builtin_amdgcn_s_setprio(1);
        #pragma unroll
        for (int ds = 0; ds < 2; ++ds) {
            bf16x8 pb_ = *reinterpret_cast<const bf16x8*>(&wp_lds[w][c][32 * ds + 8 * g]);
            #pragma unroll
            for (int ot = 0; ot < 6; ++ot) {
                bf16x8 a = *reinterpret_cast<const bf16x8*>(
                    vbP + (size_t)(16 * ot + c) * TSEQ + k0 + 32 * ds + 8 * g);
                acc_o[ot] = mfma16(a, pb_, acc_o[ot]);
            }
        }
        __builtin_amdgcn_s_setprio(0);
    }

    // ---- epilogue ----
    float inv = 1.0f / lrow;
    size_t m = (size_t)b_ * TSEQ + q0 + 16 * w + c;
    bf16* ob = out + m * HID + h * HD + 4 * g;
    #pragma unroll
    for (int ot = 0; ot < 6; ++ot) {
        bf16x4 pk;
        #pragma unroll
        for (int j = 0; j < 4; ++j) pk[j] = (bf16)(acc_o[ot][j] * inv);
        *reinterpret_cast<bf16x4*>(&ob[16 * ot]) = pk;
    }
}

// ---------------- output projection ----------------
__launch_bounds__(256, 2)
__global__ void k_oproj(const bf16* __restrict__ A, const bf16* __restrict__ WT,
                        const float* __restrict__ bias, float* __restrict__ out) {
    __shared__ bf16 wt_lds[96][392];
    int m0 = blockIdx.x * 64, n0 = blockIdx.y * 96;
    int tid = threadIdx.x;
    #pragma unroll
    for (int s = 0; s < 18; ++s) {
        int cc = tid + 256 * s;
        int r = cc / 48, ch = cc % 48;
        *reinterpret_cast<int4*>(&wt_lds[r][ch * 8]) =
            *reinterpret_cast<const int4*>(WT + (size_t)(n0 + r) * HID + ch * 8);
    }
    __syncthreads();
    int lane = tid & 63, w = tid >> 6;
    int c = lane & 15, g = lane >> 4;
    const bf16* Abase = A + (size_t)(m0 + 16 * w + c) * HID + 8 * g;
    f32x4 acc[6] = {};
    for (int ks = 0; ks < 12; ++ks) {
        bf16x8 a = *reinterpret_cast<const bf16x8*>(Abase + 32 * ks);
        #pragma unroll
        for (int jt = 0; jt < 6; ++jt) {
            bf16x8 b = *reinterpret_cast<const bf16x8*>(&wt_lds[16 * jt + c][32 * ks + 8 * g]);
            acc[jt] = mfma16(a, b, acc[jt]);
        }
    }
    int rbase = m0 + 16 * w + 4 * g;
    #pragma unroll
    for (int jt = 0; jt < 6; ++jt) {
        int n = n0 + 16 * jt + c;
        float bb = bias[n];
        #pragma unroll
        for (int j = 0; j < 4; ++j)
            out[(size_t)(rbase + j) * HID + n] = acc[jt][j] + bb;
    }
}

extern "C" void kernel_launch(void* const* d_in, const int* in_sizes, int n_in,
                              void* d_out, int out_size, void* d_ws, size_t ws_size,
                              hipStream_t stream) {
    const float* hs  = (const float*)d_in[0];
    const float* pe  = (const float*)d_in[1];
    const int*   msk = (const int*)d_in[2];
    const float* Wq  = (const float*)d_in[3];
    const float* bq  = (const float*)d_in[4];
    const float* Wk  = (const float*)d_in[5];
    const float* bk  = (const float*)d_in[6];
    const float* Wv  = (const float*)d_in[7];
    const float* bv  = (const float*)d_in[8];
    const float* Wo  = (const float*)d_in[9];
    const float* bo  = (const float*)d_in[10];
    const float* Wp  = (const float*)d_in[11];
    const float* pbu = (const float*)d_in[12];
    const float* pbv = (const float*)d_in[13];

    char* ws = (char*)d_ws;
    size_t off = 0;
    auto alloc = [&](size_t b) { char* p = ws + off; off += (b + 255) & ~(size_t)255; return p; };
    bf16* Xb  = (bf16*)alloc((size_t)16384 * HID * 2);
    bf16* Pb  = (bf16*)alloc((size_t)4096 * HID * 2);
    bf16* wqT = (bf16*)alloc((size_t)HID * HID * 2);
    bf16* wkT = (bf16*)alloc((size_t)HID * HID * 2);
    bf16* wvT = (bf16*)alloc((size_t)HID * HID * 2);
    bf16* woT = (bf16*)alloc((size_t)HID * HID * 2);
    bf16* wpT = (bf16*)alloc((size_t)HID * HID * 2);
    bf16* qu  = (bf16*)alloc((size_t)NBATCH * NHEAD * TSEQ * HD * 2);
    bf16* qv  = (bf16*)alloc((size_t)NBATCH * NHEAD * TSEQ * HD * 2);
    bf16* kws = (bf16*)alloc((size_t)NBATCH * NHEAD * TSEQ * HD * 2);
    bf16* vt  = (bf16*)alloc((size_t)NBATCH * NHEAD * TSEQ * HD * 2);
    bf16* pp  = (bf16*)alloc((size_t)NHEAD * 4096 * HD * 2 + 4096);  // +slack row
    bf16* ao  = (bf16*)alloc((size_t)16384 * HID * 2);

    k_conv8<<<3072, 256, 0, stream>>>(hs, Xb, 786432);
    k_conv8<<<768, 256, 0, stream>>>(pe, Pb, 196560);
    k_convT<<<576, 256, 0, stream>>>(Wq, wqT);
    k_convT<<<576, 256, 0, stream>>>(Wk, wkT);
    k_convT<<<576, 256, 0, stream>>>(Wv, wvT);
    k_convT<<<576, 256, 0, stream>>>(Wo, woT);
    k_convT<<<576, 256, 0, stream>>>(Wp, wpT);
    k_proj<<<dim3(256, 4, 4), 256, 0, stream>>>(Xb, Pb, wqT, wkT, wvT, wpT,
                                                bq, bk, bv, pbu, pbv,
                                                qu, qv, kws, vt, pp);
    k_attn<<<1024, 256, 0, stream>>>(qu, qv, kws, vt, pp, msk, ao);
    k_oproj<<<dim3(256, 4), 256, 0, stream>>>(ao, woT, bo, (float*)d_out);
}

// Round 8
// 422.434 us; speedup vs baseline: 1.0397x; 1.0397x over previous
//
#include <hip/hip_runtime.h>
#include <hip/hip_bf16.h>

#define TSEQ 2048
#define HID 384
#define NHEAD 4
#define HD 96
#define NBATCH 8

using bf16 = __bf16;
typedef bf16 bf16x8 __attribute__((ext_vector_type(8)));
typedef bf16 bf16x4 __attribute__((ext_vector_type(4)));
typedef float f32x4 __attribute__((ext_vector_type(4)));

static __device__ __forceinline__ f32x4 mfma16(bf16x8 a, bf16x8 b, f32x4 c) {
    return __builtin_amdgcn_mfma_f32_16x16x32_bf16(a, b, c, 0, 0, 0);
}

// same-wave LDS handoff: wait ds ops without draining vmcnt; DS ops pinned
// on both sides, VMEM/VALU/MFMA may cross (mask 0x7F = all but DS*).
#define LDS_HANDOFF()                                   \
    __builtin_amdgcn_sched_barrier(0x7F);               \
    asm volatile("s_waitcnt lgkmcnt(0)");               \
    __builtin_amdgcn_sched_barrier(0x7F)

// ---------------- conversion kernels ----------------
__global__ void k_conv8(const float* __restrict__ src, bf16* __restrict__ dst, int n8) {
    int t = blockIdx.x * 256 + threadIdx.x;
    if (t >= n8) return;
    const float4* s4 = reinterpret_cast<const float4*>(src);
    float4 a = s4[2 * t], b = s4[2 * t + 1];
    bf16x8 o;
    o[0] = (bf16)a.x; o[1] = (bf16)a.y; o[2] = (bf16)a.z; o[3] = (bf16)a.w;
    o[4] = (bf16)b.x; o[5] = (bf16)b.y; o[6] = (bf16)b.z; o[7] = (bf16)b.w;
    *reinterpret_cast<bf16x8*>(dst + 8 * t) = o;
}

__global__ void k_convT(const float* __restrict__ W, bf16* __restrict__ WT) {
    int t = blockIdx.x * 256 + threadIdx.x;  // WT[n][k] = W[k][n]
    int n = t / HID, k = t % HID;
    WT[t] = (bf16)W[(size_t)k * HID + n];
}

// ---------------- projection GEMM (Q,K,V,pos) ----------------
__launch_bounds__(256, 2)
__global__ void k_proj(const bf16* __restrict__ X, const bf16* __restrict__ P,
                       const bf16* __restrict__ wqT, const bf16* __restrict__ wkT,
                       const bf16* __restrict__ wvT, const bf16* __restrict__ wpT,
                       const float* __restrict__ bq, const float* __restrict__ bk,
                       const float* __restrict__ bv,
                       const float* __restrict__ pbu, const float* __restrict__ pbv,
                       bf16* __restrict__ qu, bf16* __restrict__ qv,
                       bf16* __restrict__ kws, bf16* __restrict__ vt,
                       bf16* __restrict__ pp) {
    __shared__ bf16 wt_lds[96][392];
    const float SC = 0.10206207262f;  // 1/sqrt(96) folded into q
    int mat = blockIdx.z;             // 0=Q 1=K 2=V 3=POS
    int m0 = blockIdx.x * 64;
    if (mat == 3 && m0 >= 4095) return;
    int n0 = blockIdx.y * 96;
    const bf16* A  = (mat == 3) ? P : X;
    const bf16* WT = (mat == 0) ? wqT : (mat == 1) ? wkT : (mat == 2) ? wvT : wpT;
    int tid = threadIdx.x;
    #pragma unroll
    for (int s = 0; s < 18; ++s) {
        int cc = tid + 256 * s;
        int r = cc / 48, ch = cc % 48;
        *reinterpret_cast<int4*>(&wt_lds[r][ch * 8]) =
            *reinterpret_cast<const int4*>(WT + (size_t)(n0 + r) * HID + ch * 8);
    }
    __syncthreads();
    int lane = tid & 63, w = tid >> 6;
    int c = lane & 15, g = lane >> 4;
    int arow = m0 + 16 * w + c;
    if (mat == 3 && arow > 4095) arow = 4095;
    const bf16* Abase = A + (size_t)arow * HID + 8 * g;
    f32x4 acc[6] = {};
    for (int ks = 0; ks < 12; ++ks) {
        bf16x8 a = *reinterpret_cast<const bf16x8*>(Abase + 32 * ks);
        #pragma unroll
        for (int jt = 0; jt < 6; ++jt) {
            bf16x8 b = *reinterpret_cast<const bf16x8*>(&wt_lds[16 * jt + c][32 * ks + 8 * g]);
            acc[jt] = mfma16(a, b, acc[jt]);
        }
    }
    int h = blockIdx.y;
    int rbase = m0 + 16 * w + 4 * g;
    if (mat == 0) {
        #pragma unroll
        for (int jt = 0; jt < 6; ++jt) {
            int n = n0 + 16 * jt + c;
            int d = 16 * jt + c;
            float bb = bq[n], bu = pbu[n], bvv = pbv[n];
            #pragma unroll
            for (int j = 0; j < 4; ++j) {
                int m = rbase + j;
                int b_ = m >> 11, t = m & 2047;
                size_t o = (((size_t)(b_ * NHEAD + h)) * TSEQ + t) * HD + d;
                float q = acc[jt][j] + bb;
                qu[o] = (bf16)((q + bu) * SC);
                qv[o] = (bf16)((q + bvv) * SC);
            }
        }
    } else if (mat == 1) {
        #pragma unroll
        for (int jt = 0; jt < 6; ++jt) {
            int n = n0 + 16 * jt + c;
            int d = 16 * jt + c;
            float bb = bk[n];
            #pragma unroll
            for (int j = 0; j < 4; ++j) {
                int m = rbase + j;
                int b_ = m >> 11, t = m & 2047;
                size_t o = (((size_t)(b_ * NHEAD + h)) * TSEQ + t) * HD + d;
                kws[o] = (bf16)(acc[jt][j] + bb);
            }
        }
    } else if (mat == 2) {
        #pragma unroll
        for (int jt = 0; jt < 6; ++jt) {
            int d = 16 * jt + c;
            float bb = bv[n0 + 16 * jt + c];
            int m = rbase;
            int b_ = m >> 11, t0 = m & 2047;
            size_t o = (((size_t)(b_ * NHEAD + h)) * HD + d) * TSEQ + t0;
            bf16x4 pk;
            #pragma unroll
            for (int j = 0; j < 4; ++j) pk[j] = (bf16)(acc[jt][j] + bb);
            *reinterpret_cast<bf16x4*>(vt + o) = pk;
        }
    } else {
        #pragma unroll
        for (int jt = 0; jt < 6; ++jt) {
            int d = 16 * jt + c;
            #pragma unroll
            for (int j = 0; j < 4; ++j) {
                int m = rbase + j;
                if (m < 4095) {
                    size_t o = ((size_t)h * 4096 + m) * HD + d;
                    pp[o] = (bf16)acc[jt][j];
                }
            }
        }
    }
}

// ---------------- fused rel-pos flash attention (transposed-S, all-global) ----
// grid 1024 = 8 XCD groups x 128; K/V/pos MFMA A-frags direct from global (L2;
// per-XCD working set ~3.8MB). NO barriers — waves fully independent. All ~37
// loads of an iteration are HOISTED to the top and held in registers (256-reg
// tier, 2 waves/SIMD): K consumed after the win phase (~400cyc), V at the end
// (~800cyc) — L2 latency hidden in-order. (r7 lesson: same structure at the
// 64-reg tier serializes loads -> 382us.)
// S^T = mfma(K,Qu): lane(c,g) reg(t,j) holds S^T[k=16t+4g+j][q=c].
// Win tile t=4 of iter kt == t=0 of kt+1 -> register carry.
__launch_bounds__(256, 2)
__global__ void k_attn(const bf16* __restrict__ qu, const bf16* __restrict__ qv,
                       const bf16* __restrict__ kws, const bf16* __restrict__ vt,
                       const bf16* __restrict__ pp, const int* __restrict__ mask,
                       bf16* __restrict__ out) {
    __shared__ bf16 wp_lds[4][16][104];   // win (skew c+1) THEN P — time-disjoint alias

    int bid = blockIdx.x;
    // XCD-local decode: XCD x = bid&7 gets head h=x&3, batches (x>>2)*4 + (j5>>5)
    int x = bid & 7, j5 = bid >> 3;
    int h = x & 3;
    int b_ = (x >> 2) * 4 + (j5 >> 5);
    int qb = j5 & 31;
    int bh = b_ * NHEAD + h;
    int q0 = qb * 64;

    int tid = threadIdx.x, lane = tid & 63, w = tid >> 6;
    int c = lane & 15, g = lane >> 4;
    const int n_base0 = TSEQ - 1 - 63 - q0;  // lowest pos row for kt=0
    const float L2E = 1.44269504089f;
    int sw = 48 - 16 * w;                    // wave's window start offset

    const bf16* kbP = kws + (size_t)bh * TSEQ * HD;
    const bf16* vbP = vt + (size_t)bh * HD * TSEQ;
    const bf16* pbP = pp + (size_t)h * 4096 * HD;
    const int*  mbP = mask + b_ * TSEQ;

    bf16x8 qu_f[3], qv_f[3];
    {
        size_t rowbase = ((size_t)bh * TSEQ + q0 + 16 * w + c) * HD + 8 * g;
        #pragma unroll
        for (int ds = 0; ds < 3; ++ds) {
            qu_f[ds] = *reinterpret_cast<const bf16x8*>(qu + rowbase + 32 * ds);
            qv_f[ds] = *reinterpret_cast<const bf16x8*>(qv + rowbase + 32 * ds);
        }
    }

    f32x4 acc_o[6] = {};
    float mrow = -3.0e38f, lrow = 0.f;

    // ---- win carry: tile t=0 of kt=0 ----
    f32x4 wc = {};
    {
        const bf16* p0 = pbP + (size_t)(n_base0 + sw + c) * HD + 8 * g;
        #pragma unroll
        for (int ds = 0; ds < 3; ++ds)
            wc = mfma16(*reinterpret_cast<const bf16x8*>(p0 + 32 * ds), qv_f[ds], wc);
    }

    for (int kt = 0; kt < 32; ++kt) {
        int k0 = kt * 64;
        int wbase = n_base0 + 64 * kt + sw;

        // ======== hoisted loads: issue everything, consume late ========
        int mk = mbP[k0 + lane];
        bf16x8 pf[3][4];   // pos tiles 1..4 (tile 0 carried in wc)
        #pragma unroll
        for (int t = 0; t < 4; ++t) {
            const bf16* p = pbP + (size_t)(wbase + 16 * (t + 1) + c) * HD + 8 * g;
            #pragma unroll
            for (int ds = 0; ds < 3; ++ds)
                pf[ds][t] = *reinterpret_cast<const bf16x8*>(p + 32 * ds);
        }
        bf16x8 kf[3][4];   // K A-frags for QK (consumed after win phase)
        #pragma unroll
        for (int t = 0; t < 4; ++t) {
            const bf16* p = kbP + (size_t)(k0 + 16 * t + c) * HD + 8 * g;
            #pragma unroll
            for (int ds = 0; ds < 3; ++ds)
                kf[ds][t] = *reinterpret_cast<const bf16x8*>(p + 32 * ds);
        }
        bf16x8 vf[2][6];   // V^T A-frags for PV (consumed at iteration end)
        #pragma unroll
        for (int ot = 0; ot < 6; ++ot) {
            const bf16* p = vbP + (size_t)(16 * ot + c) * TSEQ + k0 + 8 * g;
            #pragma unroll
            for (int ds = 0; ds < 2; ++ds)
                vf[ds][ot] = *reinterpret_cast<const bf16x8*>(p + 32 * ds);
        }
        unsigned long long bm = __ballot(mk != 0);

        // ======== win: spill carry as tile 0; tiles 1..4 from pf; wc <- t4
        #pragma unroll
        for (int j = 0; j < 4; ++j)
            wp_lds[w][c][4 * g + j + c + 1] = (bf16)wc[j];
        {
            f32x4 w1 = {}, w2 = {}, w3 = {}, w4 = {};
            #pragma unroll
            for (int ds = 0; ds < 3; ++ds) {
                w1 = mfma16(pf[ds][0], qv_f[ds], w1);
                w2 = mfma16(pf[ds][1], qv_f[ds], w2);
                w3 = mfma16(pf[ds][2], qv_f[ds], w3);
                w4 = mfma16(pf[ds][3], qv_f[ds], w4);
            }
            #pragma unroll
            for (int j = 0; j < 4; ++j) {
                wp_lds[w][c][16 + 4 * g + j + c + 1] = (bf16)w1[j];
                wp_lds[w][c][32 + 4 * g + j + c + 1] = (bf16)w2[j];
                wp_lds[w][c][48 + 4 * g + j + c + 1] = (bf16)w3[j];
                wp_lds[w][c][64 + 4 * g + j + c + 1] = (bf16)w4[j];
            }
            wc = w4;
        }

        // ======== content scores S^T from register K-frags ========
        __builtin_amdgcn_s_setprio(1);
        f32x4 acc_s[4] = {};
        #pragma unroll
        for (int ds = 0; ds < 3; ++ds) {
            #pragma unroll
            for (int t = 0; t < 4; ++t)
                acc_s[t] = mfma16(kf[ds][t], qu_f[ds], acc_s[t]);
        }
        __builtin_amdgcn_s_setprio(0);

        LDS_HANDOFF();  // win spills -> diagonal gather (cross-lane, same wave)

        // ======== assemble + mask + online softmax (per-lane row q=c) ========
        #pragma unroll
        for (int t = 0; t < 4; ++t) {
            bf16x4 wv = *reinterpret_cast<const bf16x4*>(&wp_lds[w][c][16 * t + 4 * g + 16]);
            acc_s[t][0] += (float)wv[0];
            acc_s[t][1] += (float)wv[1];
            acc_s[t][2] += (float)wv[2];
            acc_s[t][3] += (float)wv[3];
        }
        if (bm != ~0ull) {  // wave-uniform skip: mask rarely sparse
            #pragma unroll
            for (int t = 0; t < 4; ++t)
                #pragma unroll
                for (int j = 0; j < 4; ++j)
                    if (!((bm >> (16 * t + 4 * g + j)) & 1)) acc_s[t][j] = -3.0e38f;
        }
        float pm = acc_s[0][0];
        #pragma unroll
        for (int t = 0; t < 4; ++t)
            #pragma unroll
            for (int j = 0; j < 4; ++j) pm = fmaxf(pm, acc_s[t][j]);
        pm = fmaxf(pm, __shfl_xor(pm, 16));
        pm = fmaxf(pm, __shfl_xor(pm, 32));
        if (!__all(pm <= mrow + 8.0f)) {   // defer-max (THR=8)
            float mnew = fmaxf(mrow, pm);
            float alpha = exp2f((mrow - mnew) * L2E);
            mrow = mnew; lrow *= alpha;
            #pragma unroll
            for (int ot = 0; ot < 6; ++ot) acc_o[ot] *= alpha;
        }
        float rs = 0.f;
        #pragma unroll
        for (int t = 0; t < 4; ++t)
            #pragma unroll
            for (int j = 0; j < 4; ++j) {
                float p = exp2f((acc_s[t][j] - mrow) * L2E);
                acc_s[t][j] = p; rs += p;
            }
        rs += __shfl_xor(rs, 16);
        rs += __shfl_xor(rs, 32);
        lrow += rs;

        // ======== P -> LDS (col-major [q][k], aligned b64), aliases win ========
        #pragma unroll
        for (int t = 0; t < 4; ++t) {
            bf16x4 pk;
            #pragma unroll
            for (int j = 0; j < 4; ++j) pk[j] = (bf16)acc_s[t][j];
            *reinterpret_cast<bf16x4*>(&wp_lds[w][c][16 * t + 4 * g]) = pk;
        }

        LDS_HANDOFF();  // P spills -> PV B-frags (cross-lane, same wave)

        // ======== PV: O^T += V^T . P from register V-frags ========
        __builtin_amdgcn_s_setprio(1);
        #pragma unroll
        for (int ds = 0; ds < 2; ++ds) {
            bf16x8 pb_ = *reinterpret_cast<const bf16x8*>(&wp_lds[w][c][32 * ds + 8 * g]);
            #pragma unroll
            for (int ot = 0; ot < 6; ++ot)
                acc_o[ot] = mfma16(vf[ds][ot], pb_, acc_o[ot]);
        }
        __builtin_amdgcn_s_setprio(0);
    }

    // ---- epilogue ----
    float inv = 1.0f / lrow;
    size_t m = (size_t)b_ * TSEQ + q0 + 16 * w + c;
    bf16* ob = out + m * HID + h * HD + 4 * g;
    #pragma unroll
    for (int ot = 0; ot < 6; ++ot) {
        bf16x4 pk;
        #pragma unroll
        for (int j = 0; j < 4; ++j) pk[j] = (bf16)(acc_o[ot][j] * inv);
        *reinterpret_cast<bf16x4*>(&ob[16 * ot]) = pk;
    }
}

// ---------------- output projection ----------------
__launch_bounds__(256, 2)
__global__ void k_oproj(const bf16* __restrict__ A, const bf16* __restrict__ WT,
                        const float* __restrict__ bias, float* __restrict__ out) {
    __shared__ bf16 wt_lds[96][392];
    int m0 = blockIdx.x * 64, n0 = blockIdx.y * 96;
    int tid = threadIdx.x;
    #pragma unroll
    for (int s = 0; s < 18; ++s) {
        int cc = tid + 256 * s;
        int r = cc / 48, ch = cc % 48;
        *reinterpret_cast<int4*>(&wt_lds[r][ch * 8]) =
            *reinterpret_cast<const int4*>(WT + (size_t)(n0 + r) * HID + ch * 8);
    }
    __syncthreads();
    int lane = tid & 63, w = tid >> 6;
    int c = lane & 15, g = lane >> 4;
    const bf16* Abase = A + (size_t)(m0 + 16 * w + c) * HID + 8 * g;
    f32x4 acc[6] = {};
    for (int ks = 0; ks < 12; ++ks) {
        bf16x8 a = *reinterpret_cast<const bf16x8*>(Abase + 32 * ks);
        #pragma unroll
        for (int jt = 0; jt < 6; ++jt) {
            bf16x8 b = *reinterpret_cast<const bf16x8*>(&wt_lds[16 * jt + c][32 * ks + 8 * g]);
            acc[jt] = mfma16(a, b, acc[jt]);
        }
    }
    int rbase = m0 + 16 * w + 4 * g;
    #pragma unroll
    for (int jt = 0; jt < 6; ++jt) {
        int n = n0 + 16 * jt + c;
        float bb = bias[n];
        #pragma unroll
        for (int j = 0; j < 4; ++j)
            out[(size_t)(rbase + j) * HID + n] = acc[jt][j] + bb;
    }
}

extern "C" void kernel_launch(void* const* d_in, const int* in_sizes, int n_in,
                              void* d_out, int out_size, void* d_ws, size_t ws_size,
                              hipStream_t stream) {
    const float* hs  = (const float*)d_in[0];
    const float* pe  = (const float*)d_in[1];
    const int*   msk = (const int*)d_in[2];
    const float* Wq  = (const float*)d_in[3];
    const float* bq  = (const float*)d_in[4];
    const float* Wk  = (const float*)d_in[5];
    const float* bk  = (const float*)d_in[6];
    const float* Wv  = (const float*)d_in[7];
    const float* bv  = (const float*)d_in[8];
    const float* Wo  = (const float*)d_in[9];
    const float* bo  = (const float*)d_in[10];
    const float* Wp  = (const float*)d_in[11];
    const float* pbu = (const float*)d_in[12];
    const float* pbv = (const float*)d_in[13];

    char* ws = (char*)d_ws;
    size_t off = 0;
    auto alloc = [&](size_t b) { char* p = ws + off; off += (b + 255) & ~(size_t)255; return p; };
    bf16* Xb  = (bf16*)alloc((size_t)16384 * HID * 2);
    bf16* Pb  = (bf16*)alloc((size_t)4096 * HID * 2);
    bf16* wqT = (bf16*)alloc((size_t)HID * HID * 2);
    bf16* wkT = (bf16*)alloc((size_t)HID * HID * 2);
    bf16* wvT = (bf16*)alloc((size_t)HID * HID * 2);
    bf16* woT = (bf16*)alloc((size_t)HID * HID * 2);
    bf16* wpT = (bf16*)alloc((size_t)HID * HID * 2);
    bf16* qu  = (bf16*)alloc((size_t)NBATCH * NHEAD * TSEQ * HD * 2);
    bf16* qv  = (bf16*)alloc((size_t)NBATCH * NHEAD * TSEQ * HD * 2);
    bf16* kws = (bf16*)alloc((size_t)NBATCH * NHEAD * TSEQ * HD * 2);
    bf16* vt  = (bf16*)alloc((size_t)NBATCH * NHEAD * TSEQ * HD * 2);
    bf16* pp  = (bf16*)alloc((size_t)NHEAD * 4096 * HD * 2 + 4096);  // +slack row
    bf16* ao  = (bf16*)alloc((size_t)16384 * HID * 2);

    k_conv8<<<3072, 256, 0, stream>>>(hs, Xb, 786432);
    k_conv8<<<768, 256, 0, stream>>>(pe, Pb, 196560);
    k_convT<<<576, 256, 0, stream>>>(Wq, wqT);
    k_convT<<<576, 256, 0, stream>>>(Wk, wkT);
    k_convT<<<576, 256, 0, stream>>>(Wv, wvT);
    k_convT<<<576, 256, 0, stream>>>(Wo, woT);
    k_convT<<<576, 256, 0, stream>>>(Wp, wpT);
    k_proj<<<dim3(256, 4, 4), 256, 0, stream>>>(Xb, Pb, wqT, wkT, wvT, wpT,
                                                bq, bk, bv, pbu, pbv,
                                                qu, qv, kws, vt, pp);
    k_attn<<<1024, 256, 0, stream>>>(qu, qv, kws, vt, pp, msk, ao);
    k_oproj<<<dim3(256, 4), 256, 0, stream>>>(ao, woT, bo, (float*)d_out);
}

// Round 9
// 289.285 us; speedup vs baseline: 1.5183x; 1.4603x over previous
//
#include <hip/hip_runtime.h>
#include <hip/hip_bf16.h>

#define TSEQ 2048
#define HID 384
#define NHEAD 4
#define HD 96
#define NBATCH 8

using bf16 = __bf16;
typedef bf16 bf16x8 __attribute__((ext_vector_type(8)));
typedef bf16 bf16x4 __attribute__((ext_vector_type(4)));
typedef float f32x4 __attribute__((ext_vector_type(4)));

static __device__ __forceinline__ f32x4 mfma16(bf16x8 a, bf16x8 b, f32x4 c) {
    return __builtin_amdgcn_mfma_f32_16x16x32_bf16(a, b, c, 0, 0, 0);
}

// same-wave LDS handoff: wait ds ops without draining vmcnt; DS pinned both
// sides, VMEM/VALU/MFMA may cross (mask 0x7F = all but DS*).
#define LDS_HANDOFF()                                   \
    __builtin_amdgcn_sched_barrier(0x7F);               \
    asm volatile("s_waitcnt lgkmcnt(0)");               \
    __builtin_amdgcn_sched_barrier(0x7F)

// async global->LDS DMA, 16B per lane; LDS dest = wave-uniform base + lane*16.
#define GL2LDS(g, l) __builtin_amdgcn_global_load_lds(                        \
    (const __attribute__((address_space(1))) unsigned int*)(const void*)(g),  \
    (__attribute__((address_space(3))) unsigned int*)(void*)(l), 16, 0, 0)

// ---------------- conversion kernels ----------------
__global__ void k_conv8(const float* __restrict__ src, bf16* __restrict__ dst, int n8) {
    int t = blockIdx.x * 256 + threadIdx.x;
    if (t >= n8) return;
    const float4* s4 = reinterpret_cast<const float4*>(src);
    float4 a = s4[2 * t], b = s4[2 * t + 1];
    bf16x8 o;
    o[0] = (bf16)a.x; o[1] = (bf16)a.y; o[2] = (bf16)a.z; o[3] = (bf16)a.w;
    o[4] = (bf16)b.x; o[5] = (bf16)b.y; o[6] = (bf16)b.z; o[7] = (bf16)b.w;
    *reinterpret_cast<bf16x8*>(dst + 8 * t) = o;
}

__global__ void k_convT(const float* __restrict__ W, bf16* __restrict__ WT) {
    int t = blockIdx.x * 256 + threadIdx.x;  // WT[n][k] = W[k][n]
    int n = t / HID, k = t % HID;
    WT[t] = (bf16)W[(size_t)k * HID + n];
}

// ---------------- projection GEMM (Q,K,V,pos) ----------------
__launch_bounds__(256, 2)
__global__ void k_proj(const bf16* __restrict__ X, const bf16* __restrict__ P,
                       const bf16* __restrict__ wqT, const bf16* __restrict__ wkT,
                       const bf16* __restrict__ wvT, const bf16* __restrict__ wpT,
                       const float* __restrict__ bq, const float* __restrict__ bk,
                       const float* __restrict__ bv,
                       const float* __restrict__ pbu, const float* __restrict__ pbv,
                       bf16* __restrict__ qu, bf16* __restrict__ qv,
                       bf16* __restrict__ kws, bf16* __restrict__ vt,
                       bf16* __restrict__ pp) {
    __shared__ bf16 wt_lds[96][392];
    const float SC = 0.10206207262f;  // 1/sqrt(96) folded into q
    int mat = blockIdx.z;             // 0=Q 1=K 2=V 3=POS
    int m0 = blockIdx.x * 64;
    if (mat == 3 && m0 >= 4095) return;
    int n0 = blockIdx.y * 96;
    const bf16* A  = (mat == 3) ? P : X;
    const bf16* WT = (mat == 0) ? wqT : (mat == 1) ? wkT : (mat == 2) ? wvT : wpT;
    int tid = threadIdx.x;
    #pragma unroll
    for (int s = 0; s < 18; ++s) {
        int cc = tid + 256 * s;
        int r = cc / 48, ch = cc % 48;
        *reinterpret_cast<int4*>(&wt_lds[r][ch * 8]) =
            *reinterpret_cast<const int4*>(WT + (size_t)(n0 + r) * HID + ch * 8);
    }
    __syncthreads();
    int lane = tid & 63, w = tid >> 6;
    int c = lane & 15, g = lane >> 4;
    int arow = m0 + 16 * w + c;
    if (mat == 3 && arow > 4095) arow = 4095;
    const bf16* Abase = A + (size_t)arow * HID + 8 * g;
    f32x4 acc[6] = {};
    for (int ks = 0; ks < 12; ++ks) {
        bf16x8 a = *reinterpret_cast<const bf16x8*>(Abase + 32 * ks);
        #pragma unroll
        for (int jt = 0; jt < 6; ++jt) {
            bf16x8 b = *reinterpret_cast<const bf16x8*>(&wt_lds[16 * jt + c][32 * ks + 8 * g]);
            acc[jt] = mfma16(a, b, acc[jt]);
        }
    }
    int h = blockIdx.y;
    int rbase = m0 + 16 * w + 4 * g;
    if (mat == 0) {
        #pragma unroll
        for (int jt = 0; jt < 6; ++jt) {
            int n = n0 + 16 * jt + c;
            int d = 16 * jt + c;
            float bb = bq[n], bu = pbu[n], bvv = pbv[n];
            #pragma unroll
            for (int j = 0; j < 4; ++j) {
                int m = rbase + j;
                int b_ = m >> 11, t = m & 2047;
                size_t o = (((size_t)(b_ * NHEAD + h)) * TSEQ + t) * HD + d;
                float q = acc[jt][j] + bb;
                qu[o] = (bf16)((q + bu) * SC);
                qv[o] = (bf16)((q + bvv) * SC);
            }
        }
    } else if (mat == 1) {
        #pragma unroll
        for (int jt = 0; jt < 6; ++jt) {
            int n = n0 + 16 * jt + c;
            int d = 16 * jt + c;
            float bb = bk[n];
            #pragma unroll
            for (int j = 0; j < 4; ++j) {
                int m = rbase + j;
                int b_ = m >> 11, t = m & 2047;
                size_t o = (((size_t)(b_ * NHEAD + h)) * TSEQ + t) * HD + d;
                kws[o] = (bf16)(acc[jt][j] + bb);
            }
        }
    } else if (mat == 2) {
        #pragma unroll
        for (int jt = 0; jt < 6; ++jt) {
            int d = 16 * jt + c;
            float bb = bv[n0 + 16 * jt + c];
            int m = rbase;
            int b_ = m >> 11, t0 = m & 2047;
            size_t o = (((size_t)(b_ * NHEAD + h)) * HD + d) * TSEQ + t0;
            bf16x4 pk;
            #pragma unroll
            for (int j = 0; j < 4; ++j) pk[j] = (bf16)(acc[jt][j] + bb);
            *reinterpret_cast<bf16x4*>(vt + o) = pk;
        }
    } else {
        #pragma unroll
        for (int jt = 0; jt < 6; ++jt) {
            int d = 16 * jt + c;
            #pragma unroll
            for (int j = 0; j < 4; ++j) {
                int m = rbase + j;
                if (m < 4095) {
                    size_t o = ((size_t)h * 4096 + m) * HD + d;
                    pp[o] = (bf16)acc[jt][j];
                }
            }
        }
    }
}

// ---------------- fused rel-pos flash attention ----------------
// r6 structure (4 blocks/CU: LDS 38.9KB, arch+acc regs <=128) with the WIN
// phase software-pipelined one iteration ahead: win[kt+1] (pos-only, independent
// of tile kt) is computed AFTER PV of iter kt into the same per-wave buffer
// (same-wave DS in-order: gather of win[kt] precedes the overwrite). Iteration
// start is then a latency-free b64 gather. Mask via ballot (no msk_lds).
// V staged by global_load_lds (linear LDS dest + pre-swizzled global src).
// S^T = mfma(K,Qu): lane(c,g) reg(t,j) holds S^T[k=16t+4g+j][q=c].
__launch_bounds__(256, 4)
__global__ void k_attn(const bf16* __restrict__ qu, const bf16* __restrict__ qv,
                       const bf16* __restrict__ kws, const bf16* __restrict__ vt,
                       const bf16* __restrict__ pp, const int* __restrict__ mask,
                       bf16* __restrict__ out) {
    __shared__ bf16 k_lds[64][104];       // K tile, padded rows (read ~2-way)
    __shared__ bf16 vt_lds[96][64];       // V^T tile, 16B-chunk XOR swizzle
    __shared__ bf16 wp_lds[4][16][104];   // win (skew c+1) / P — time-phased

    int bid = blockIdx.x;
    // XCD-local decode: XCD x = bid&7 gets head h=x&3, batches (x>>2)*4 + (j5>>5)
    int x = bid & 7, j5 = bid >> 3;
    int h = x & 3;
    int b_ = (x >> 2) * 4 + (j5 >> 5);
    int qb = j5 & 31;
    int bh = b_ * NHEAD + h;
    int q0 = qb * 64;

    int tid = threadIdx.x, lane = tid & 63, w = tid >> 6;
    int c = lane & 15, g = lane >> 4;
    const int n_base0 = TSEQ - 1 - 63 - q0;  // lowest pos row for kt=0
    const float L2E = 1.44269504089f;
    int sw = 48 - 16 * w;                    // wave's window start offset

    // ---- kt-invariant staging coordinates ----
    int cc0 = tid, cc1 = tid + 256, cc2 = tid + 512;
    int kr0 = cc0 / 12, kc0 = cc0 % 12;
    int kr1 = cc1 / 12, kc1 = cc1 % 12;
    int kr2 = cc2 / 12, kc2 = cc2 % 12;
    int kO0 = kr0 * HD + kc0 * 8, kO1 = kr1 * HD + kc1 * 8, kO2 = kr2 * HD + kc2 * 8;
    bf16* kP0 = &k_lds[kr0][kc0 * 8];
    bf16* kP1 = &k_lds[kr1][kc1 * 8];
    bf16* kP2 = &k_lds[kr2][kc2 * 8];
    // V via global_load_lds: slot cc (linear, 16B) <- global chunk (r, ch^(r&7))
    int vr0 = cc0 >> 3, vc0 = cc0 & 7;
    int vr1 = cc1 >> 3, vc1 = cc1 & 7;
    int vr2 = cc2 >> 3, vc2 = cc2 & 7;
    int vO0 = vr0 * TSEQ + (vc0 ^ (vr0 & 7)) * 8;
    int vO1 = vr1 * TSEQ + (vc1 ^ (vr1 & 7)) * 8;
    int vO2 = vr2 * TSEQ + (vc2 ^ (vr2 & 7)) * 8;
    bf16* vt_flat = &vt_lds[0][0];
    bf16* vL0 = vt_flat + (size_t)(0 * 256 + 64 * w) * 8;   // wave-uniform bases
    bf16* vL1 = vt_flat + (size_t)(1 * 256 + 64 * w) * 8;
    bf16* vL2 = vt_flat + (size_t)(2 * 256 + 64 * w) * 8;

    const bf16* kbP = kws + (size_t)bh * TSEQ * HD;
    const bf16* vbP = vt + (size_t)bh * HD * TSEQ;
    const bf16* pbP = pp + (size_t)h * 4096 * HD;
    const int*  mbP = mask + b_ * TSEQ;

    bf16x8 qu_f[3], qv_f[3];
    {
        size_t rowbase = ((size_t)bh * TSEQ + q0 + 16 * w + c) * HD + 8 * g;
        #pragma unroll
        for (int ds = 0; ds < 3; ++ds) {
            qu_f[ds] = *reinterpret_cast<const bf16x8*>(qu + rowbase + 32 * ds);
            qv_f[ds] = *reinterpret_cast<const bf16x8*>(qv + rowbase + 32 * ds);
        }
    }

    f32x4 acc_o[6] = {};
    float mrow = -3.0e38f, lrow = 0.f;
    f32x4 wc;  // win carry: tile4 of iter kt == tile0 of kt+1

    // ---- prologue: stage tile 0 (V-DMA + K), win[0] compute+spill ----
    {
        GL2LDS(vbP + vO0, vL0);
        GL2LDS(vbP + vO1, vL1);
        GL2LDS(vbP + vO2, vL2);
        *reinterpret_cast<int4*>(kP0) = *reinterpret_cast<const int4*>(kbP + kO0);
        *reinterpret_cast<int4*>(kP1) = *reinterpret_cast<const int4*>(kbP + kO1);
        *reinterpret_cast<int4*>(kP2) = *reinterpret_cast<const int4*>(kbP + kO2);

        int wb = n_base0 + sw;
        f32x4 w0 = {};
        {
            const bf16* p0 = pbP + (size_t)(wb + c) * HD + 8 * g;
            #pragma unroll
            for (int ds = 0; ds < 3; ++ds)
                w0 = mfma16(*reinterpret_cast<const bf16x8*>(p0 + 32 * ds), qv_f[ds], w0);
            #pragma unroll
            for (int j = 0; j < 4; ++j)
                wp_lds[w][c][4 * g + j + c + 1] = (bf16)w0[j];
        }
        {
            f32x4 w1 = {}, w2 = {}, w3 = {}, w4 = {};
            const bf16* p1 = pbP + (size_t)(wb + 16 + c) * HD + 8 * g;
            const bf16* p2 = pbP + (size_t)(wb + 32 + c) * HD + 8 * g;
            const bf16* p3 = pbP + (size_t)(wb + 48 + c) * HD + 8 * g;
            const bf16* p4 = pbP + (size_t)(wb + 64 + c) * HD + 8 * g;
            #pragma unroll
            for (int ds = 0; ds < 3; ++ds) {
                w1 = mfma16(*reinterpret_cast<const bf16x8*>(p1 + 32 * ds), qv_f[ds], w1);
                w2 = mfma16(*reinterpret_cast<const bf16x8*>(p2 + 32 * ds), qv_f[ds], w2);
                w3 = mfma16(*reinterpret_cast<const bf16x8*>(p3 + 32 * ds), qv_f[ds], w3);
                w4 = mfma16(*reinterpret_cast<const bf16x8*>(p4 + 32 * ds), qv_f[ds], w4);
            }
            #pragma unroll
            for (int j = 0; j < 4; ++j) {
                wp_lds[w][c][16 + 4 * g + j + c + 1] = (bf16)w1[j];
                wp_lds[w][c][32 + 4 * g + j + c + 1] = (bf16)w2[j];
                wp_lds[w][c][48 + 4 * g + j + c + 1] = (bf16)w3[j];
                wp_lds[w][c][64 + 4 * g + j + c + 1] = (bf16)w4[j];
            }
            wc = w4;
        }
    }
    __syncthreads();  // drains vmcnt (V-DMA) + lgkm (K writes, win spills)

    for (int kt = 0; kt < 32; ++kt) {
        int k0 = kt * 64;
        unsigned long long bm = __ballot(mbP[k0 + lane] != 0);

        // ---- gather win[kt] (spilled last iter; drained by barrier) ----
        bf16x4 wv0 = *reinterpret_cast<const bf16x4*>(&wp_lds[w][c][4 * g + 16]);
        bf16x4 wv1 = *reinterpret_cast<const bf16x4*>(&wp_lds[w][c][16 + 4 * g + 16]);
        bf16x4 wv2 = *reinterpret_cast<const bf16x4*>(&wp_lds[w][c][32 + 4 * g + 16]);
        bf16x4 wv3 = *reinterpret_cast<const bf16x4*>(&wp_lds[w][c][48 + 4 * g + 16]);

        // ---- content scores S^T (K from LDS) ----
        __builtin_amdgcn_s_setprio(1);
        f32x4 acc_s[4] = {};
        #pragma unroll
        for (int ds = 0; ds < 3; ++ds) {
            #pragma unroll
            for (int t = 0; t < 4; ++t) {
                bf16x8 a = *reinterpret_cast<const bf16x8*>(&k_lds[16 * t + c][32 * ds + 8 * g]);
                acc_s[t] = mfma16(a, qu_f[ds], acc_s[t]);
            }
        }
        __builtin_amdgcn_s_setprio(0);

        // ---- assemble + mask + online softmax (per-lane row q=c) ----
        acc_s[0][0] += (float)wv0[0]; acc_s[0][1] += (float)wv0[1];
        acc_s[0][2] += (float)wv0[2]; acc_s[0][3] += (float)wv0[3];
        acc_s[1][0] += (float)wv1[0]; acc_s[1][1] += (float)wv1[1];
        acc_s[1][2] += (float)wv1[2]; acc_s[1][3] += (float)wv1[3];
        acc_s[2][0] += (float)wv2[0]; acc_s[2][1] += (float)wv2[1];
        acc_s[2][2] += (float)wv2[2]; acc_s[2][3] += (float)wv2[3];
        acc_s[3][0] += (float)wv3[0]; acc_s[3][1] += (float)wv3[1];
        acc_s[3][2] += (float)wv3[2]; acc_s[3][3] += (float)wv3[3];
        if (bm != ~0ull) {
            #pragma unroll
            for (int t = 0; t < 4; ++t)
                #pragma unroll
                for (int j = 0; j < 4; ++j)
                    if (!((bm >> (16 * t + 4 * g + j)) & 1)) acc_s[t][j] = -3.0e38f;
        }
        float pm = acc_s[0][0];
        #pragma unroll
        for (int t = 0; t < 4; ++t)
            #pragma unroll
            for (int j = 0; j < 4; ++j) pm = fmaxf(pm, acc_s[t][j]);
        pm = fmaxf(pm, __shfl_xor(pm, 16));
        pm = fmaxf(pm, __shfl_xor(pm, 32));
        if (!__all(pm <= mrow + 8.0f)) {   // defer-max (THR=8)
            float mnew = fmaxf(mrow, pm);
            float alpha = exp2f((mrow - mnew) * L2E);
            mrow = mnew; lrow *= alpha;
            #pragma unroll
            for (int ot = 0; ot < 6; ++ot) acc_o[ot] *= alpha;
        }
        float rs = 0.f;
        #pragma unroll
        for (int t = 0; t < 4; ++t)
            #pragma unroll
            for (int j = 0; j < 4; ++j) {
                float p = exp2f((acc_s[t][j] - mrow) * L2E);
                acc_s[t][j] = p; rs += p;
            }
        rs += __shfl_xor(rs, 16);
        rs += __shfl_xor(rs, 32);
        lrow += rs;

        // ---- P -> LDS (col-major [q][k], aligned b64) ----
        #pragma unroll
        for (int t = 0; t < 4; ++t) {
            bf16x4 pk;
            #pragma unroll
            for (int j = 0; j < 4; ++j) pk[j] = (bf16)acc_s[t][j];
            *reinterpret_cast<bf16x4*>(&wp_lds[w][c][16 * t + 4 * g]) = pk;
        }
        LDS_HANDOFF();  // P spills -> PV B-frags (cross-lane, same wave)

        // ---- PV: O^T += V^T . P ----
        __builtin_amdgcn_s_setprio(1);
        #pragma unroll
        for (int ds = 0; ds < 2; ++ds) {
            bf16x8 pb_ = *reinterpret_cast<const bf16x8*>(&wp_lds[w][c][32 * ds + 8 * g]);
            #pragma unroll
            for (int ot = 0; ot < 6; ++ot) {
                int rr = 16 * ot + c;
                bf16x8 a = *reinterpret_cast<const bf16x8*>(
                    &vt_lds[rr][((4 * ds + g) ^ (rr & 7)) * 8]);
                acc_o[ot] = mfma16(a, pb_, acc_o[ot]);
            }
        }
        __builtin_amdgcn_s_setprio(0);

        if (kt < 31) {
            // ---- win[kt+1]: spill carry as tile0, compute tiles 1..4 ----
            // (P already consumed; overwrite is ordered by same-wave DS order)
            int wb = n_base0 + 64 * (kt + 1) + sw;
            #pragma unroll
            for (int j = 0; j < 4; ++j)
                wp_lds[w][c][4 * g + j + c + 1] = (bf16)wc[j];
            f32x4 w1 = {}, w2 = {}, w3 = {}, w4 = {};
            const bf16* p1 = pbP + (size_t)(wb + 16 + c) * HD + 8 * g;
            const bf16* p2 = pbP + (size_t)(wb + 32 + c) * HD + 8 * g;
            const bf16* p3 = pbP + (size_t)(wb + 48 + c) * HD + 8 * g;
            const bf16* p4 = pbP + (size_t)(wb + 64 + c) * HD + 8 * g;
            #pragma unroll
            for (int ds = 0; ds < 3; ++ds) {
                w1 = mfma16(*reinterpret_cast<const bf16x8*>(p1 + 32 * ds), qv_f[ds], w1);
                w2 = mfma16(*reinterpret_cast<const bf16x8*>(p2 + 32 * ds), qv_f[ds], w2);
                w3 = mfma16(*reinterpret_cast<const bf16x8*>(p3 + 32 * ds), qv_f[ds], w3);
                w4 = mfma16(*reinterpret_cast<const bf16x8*>(p4 + 32 * ds), qv_f[ds], w4);
            }
            #pragma unroll
            for (int j = 0; j < 4; ++j) {
                wp_lds[w][c][16 + 4 * g + j + c + 1] = (bf16)w1[j];
                wp_lds[w][c][32 + 4 * g + j + c + 1] = (bf16)w2[j];
                wp_lds[w][c][48 + 4 * g + j + c + 1] = (bf16)w3[j];
                wp_lds[w][c][64 + 4 * g + j + c + 1] = (bf16)w4[j];
            }
            wc = w4;

            // ---- stage tile kt+1 (all waves' LDS reads of tile kt are done
            //      only after the barrier; win spills drain at the barrier too)
            __syncthreads();
            int k0n = k0 + 64;
            const bf16* kb = kbP + (size_t)k0n * HD;
            const bf16* vb = vbP + k0n;
            GL2LDS(vb + vO0, vL0);
            GL2LDS(vb + vO1, vL1);
            GL2LDS(vb + vO2, vL2);
            *reinterpret_cast<int4*>(kP0) = *reinterpret_cast<const int4*>(kb + kO0);
            *reinterpret_cast<int4*>(kP1) = *reinterpret_cast<const int4*>(kb + kO1);
            *reinterpret_cast<int4*>(kP2) = *reinterpret_cast<const int4*>(kb + kO2);
            __syncthreads();  // drains vmcnt (V-DMA) + lgkm (K + win spills)
        }
    }

    // ---- epilogue ----
    float inv = 1.0f / lrow;
    size_t m = (size_t)b_ * TSEQ + q0 + 16 * w + c;
    bf16* ob = out + m * HID + h * HD + 4 * g;
    #pragma unroll
    for (int ot = 0; ot < 6; ++ot) {
        bf16x4 pk;
        #pragma unroll
        for (int j = 0; j < 4; ++j) pk[j] = (bf16)(acc_o[ot][j] * inv);
        *reinterpret_cast<bf16x4*>(&ob[16 * ot]) = pk;
    }
}

// ---------------- output projection ----------------
__launch_bounds__(256, 2)
__global__ void k_oproj(const bf16* __restrict__ A, const bf16* __restrict__ WT,
                        const float* __restrict__ bias, float* __restrict__ out) {
    __shared__ bf16 wt_lds[96][392];
    int m0 = blockIdx.x * 64, n0 = blockIdx.y * 96;
    int tid = threadIdx.x;
    #pragma unroll
    for (int s = 0; s < 18; ++s) {
        int cc = tid + 256 * s;
        int r = cc / 48, ch = cc % 48;
        *reinterpret_cast<int4*>(&wt_lds[r][ch * 8]) =
            *reinterpret_cast<const int4*>(WT + (size_t)(n0 + r) * HID + ch * 8);
    }
    __syncthreads();
    int lane = tid & 63, w = tid >> 6;
    int c = lane & 15, g = lane >> 4;
    const bf16* Abase = A + (size_t)(m0 + 16 * w + c) * HID + 8 * g;
    f32x4 acc[6] = {};
    for (int ks = 0; ks < 12; ++ks) {
        bf16x8 a = *reinterpret_cast<const bf16x8*>(Abase + 32 * ks);
        #pragma unroll
        for (int jt = 0; jt < 6; ++jt) {
            bf16x8 b = *reinterpret_cast<const bf16x8*>(&wt_lds[16 * jt + c][32 * ks + 8 * g]);
            acc[jt] = mfma16(a, b, acc[jt]);
        }
    }
    int rbase = m0 + 16 * w + 4 * g;
    #pragma unroll
    for (int jt = 0; jt < 6; ++jt) {
        int n = n0 + 16 * jt + c;
        float bb = bias[n];
        #pragma unroll
        for (int j = 0; j < 4; ++j)
            out[(size_t)(rbase + j) * HID + n] = acc[jt][j] + bb;
    }
}

extern "C" void kernel_launch(void* const* d_in, const int* in_sizes, int n_in,
                              void* d_out, int out_size, void* d_ws, size_t ws_size,
                              hipStream_t stream) {
    const float* hs  = (const float*)d_in[0];
    const float* pe  = (const float*)d_in[1];
    const int*   msk = (const int*)d_in[2];
    const float* Wq  = (const float*)d_in[3];
    const float* bq  = (const float*)d_in[4];
    const float* Wk  = (const float*)d_in[5];
    const float* bk  = (const float*)d_in[6];
    const float* Wv  = (const float*)d_in[7];
    const float* bv  = (const float*)d_in[8];
    const float* Wo  = (const float*)d_in[9];
    const float* bo  = (const float*)d_in[10];
    const float* Wp  = (const float*)d_in[11];
    const float* pbu = (const float*)d_in[12];
    const float* pbv = (const float*)d_in[13];

    char* ws = (char*)d_ws;
    size_t off = 0;
    auto alloc = [&](size_t b) { char* p = ws + off; off += (b + 255) & ~(size_t)255; return p; };
    bf16* Xb  = (bf16*)alloc((size_t)16384 * HID * 2);
    bf16* Pb  = (bf16*)alloc((size_t)4096 * HID * 2);
    bf16* wqT = (bf16*)alloc((size_t)HID * HID * 2);
    bf16* wkT = (bf16*)alloc((size_t)HID * HID * 2);
    bf16* wvT = (bf16*)alloc((size_t)HID * HID * 2);
    bf16* woT = (bf16*)alloc((size_t)HID * HID * 2);
    bf16* wpT = (bf16*)alloc((size_t)HID * HID * 2);
    bf16* qu  = (bf16*)alloc((size_t)NBATCH * NHEAD * TSEQ * HD * 2);
    bf16* qv  = (bf16*)alloc((size_t)NBATCH * NHEAD * TSEQ * HD * 2);
    bf16* kws = (bf16*)alloc((size_t)NBATCH * NHEAD * TSEQ * HD * 2);
    bf16* vt  = (bf16*)alloc((size_t)NBATCH * NHEAD * TSEQ * HD * 2);
    bf16* pp  = (bf16*)alloc((size_t)NHEAD * 4096 * HD * 2 + 65536);  // +slack
    bf16* ao  = (bf16*)alloc((size_t)16384 * HID * 2);

    k_conv8<<<3072, 256, 0, stream>>>(hs, Xb, 786432);
    k_conv8<<<768, 256, 0, stream>>>(pe, Pb, 196560);
    k_convT<<<576, 256, 0, stream>>>(Wq, wqT);
    k_convT<<<576, 256, 0, stream>>>(Wk, wkT);
    k_convT<<<576, 256, 0, stream>>>(Wv, wvT);
    k_convT<<<576, 256, 0, stream>>>(Wo, woT);
    k_convT<<<576, 256, 0, stream>>>(Wp, wpT);
    k_proj<<<dim3(256, 4, 4), 256, 0, stream>>>(Xb, Pb, wqT, wkT, wvT, wpT,
                                                bq, bk, bv, pbu, pbv,
                                                qu, qv, kws, vt, pp);
    k_attn<<<1024, 256, 0, stream>>>(qu, qv, kws, vt, pp, msk, ao);
    k_oproj<<<dim3(256, 4), 256, 0, stream>>>(ao, woT, bo, (float*)d_out);
}